// Round 1
// baseline (189.949 us; speedup 1.0000x reference)
//
#include <hip/hip_runtime.h>
#include <hip/hip_cooperative_groups.h>
#include <math.h>

namespace cg = cooperative_groups;

// NUM_MAPS=512, ZG=512, HID=96, SEQ=8, H1=3, H2=16, NPROC=8. fp32 in/out.
// R14: single cooperative kernel (254 blocks). Rationale: app kernels sum to
// ~12-17us; the rest of the 108us is harness floor + 2 launch gaps (~2.7us
// each, per kernel-count bracket) + serial weight entry-bursts in kB/kC.
// grid.sync() removes the gaps; idle-phase blocks pre-stage the next phase's
// weights (fc1+Wkv during phase A, fc2+Wo during phase B) so the bursts come
// off the critical path. LDS union = 16320 floats = 63.75KB static (<64KB,
// avoids the dynamic-LDS dispatch tax measured in R11/R12).
//
// Block roles (grid = 254):
//   0..143   phase A QKV1            (proc = bid&7 -> XCD)
//   144..175 phase A alpha
//   176..181 phase A q
//   182..229 [stage fc1+Wkv in A] -> phase B attn1/fc1/kv2
//   230..253 [prefetch Wq2 regs]  -> phase B Qq
//   0..63    [stage fc2/Wo/De/alpha in B window] -> phase C attn2/fc2/out

#define WS_ALPHA 0
#define WS_Q     512
#define WS_QKV   608      // 8*2304 -> 19040
#define WS_K2    19040    // 8*768  -> 25184
#define WS_V2    25184    // 8*768  -> 31328
#define WS_QQ    31328    // 8*96   -> 32096

__global__ __launch_bounds__(256) void fused_film(
    const float* __restrict__ gate, const float* __restrict__ x,
    const float* __restrict__ Wa,  const float* __restrict__ ba,
    const float* __restrict__ Wqr, const float* __restrict__ bqr,
    const float* __restrict__ P,   const float* __restrict__ De,
    const float* __restrict__ regs,
    const float* __restrict__ Wq1, const float* __restrict__ Wk1,
    const float* __restrict__ Wv1, const float* __restrict__ fc1w,
    const float* __restrict__ Wq2, const float* __restrict__ Wk2,
    const float* __restrict__ Wv2, const float* __restrict__ fc2w,
    const float* __restrict__ Wo,
    float* __restrict__ ws, float* __restrict__ out)
{
    __shared__ float lds[16320];          // 63.75 KiB union of all phases
    const int bid = blockIdx.x, tid = threadIdx.x;
    const float rs = 0.10206207261596577f;  // 1/sqrt(96)

    float wq2r[12];                       // Qq weight prefetch (bids 230..253)

    // ======================= phase-A window =======================
    if (bid < 144) {
        // QKV1: proc = bid&7 (XCD), rem -> (mat, six)
        float* sK = lds;                  // 8*528 skewed K tile
        float* sp = lds + 4224;           // 2048 partials
        const int proc = bid & 7, rem = bid >> 3;
        const int mat = rem / 6, six = rem % 6;
        const int hl = tid & 15, ks = tid >> 4;
        const int h = six * 16 + hl;
        const float* W = (mat == 0 ? Wq1 : (mat == 1 ? Wk1 : Wv1))
                         + proc * 49152 + (ks * 32) * 96 + h;
        float wreg[32];
        #pragma unroll
        for (int m2 = 0; m2 < 32; ++m2) wreg[m2] = W[m2 * 96];  // issued early
        const float4* P4 = (const float4*)(P + proc * 4096);
        for (int i = tid; i < 1024; i += 256) {
            float4 v = P4[i];
            const int c = i >> 1, off = (i & 1) * 4;
            const int cp = c + (c >> 5);
            sK[(off + 0) * 528 + cp] = v.x;
            sK[(off + 1) * 528 + cp] = v.y;
            sK[(off + 2) * 528 + cp] = v.z;
            sK[(off + 3) * 528 + cp] = v.w;
        }
        __syncthreads();
        const float* Kb = sK + ks * 33;
        float acc[8] = {0.f,0.f,0.f,0.f,0.f,0.f,0.f,0.f};
        #pragma unroll
        for (int m2 = 0; m2 < 32; ++m2) {
            const float w = wreg[m2];
            const float* Kc = Kb + m2;
            #pragma unroll
            for (int s = 0; s < 8; ++s) acc[s] += Kc[s * 528] * w;
        }
        float* spb = sp + ks * 128 + hl * 8;
        #pragma unroll
        for (int s = 0; s < 8; ++s) spb[s] = acc[s];
        __syncthreads();
        if (tid < 128) {
            float a = 0.f;
            #pragma unroll
            for (int u = 0; u < 16; ++u) a += sp[u * 128 + tid];
            const int hl2 = tid >> 3, s = tid & 7;
            ws[WS_QKV + proc * 2304 + mat * 768 + s * 96 + six * 16 + hl2] = a;
        }
    } else if (bid < 176) {
        // alpha: 16 m/blk, 16-way k-split
        float* xb = lds;
        float* sp = lds + 4224;
        const int ml = tid & 15, ks = tid >> 4;
        const int m = (bid - 144) * 16 + ml;
        const float* W = Wa + (ks * 32) * 512 + m;
        float wreg[32];
        #pragma unroll
        for (int k = 0; k < 32; ++k) wreg[k] = W[k * 512];
        for (int k = tid; k < 512; k += 256) xb[k] = x[k];
        __syncthreads();
        const float* xq = xb + ks * 32;
        float acc = 0.f;
        #pragma unroll
        for (int k = 0; k < 32; ++k) acc += xq[k] * wreg[k];
        sp[tid] = acc;
        __syncthreads();
        if (tid < 16) {
            float a = ba[(bid - 144) * 16 + tid];
            #pragma unroll
            for (int u = 0; u < 16; ++u) a += sp[u * 16 + tid];
            ws[WS_ALPHA + (bid - 144) * 16 + tid] = 1.f / (1.f + __expf(-a));
        }
    } else if (bid < 182) {
        // q: 16 h/blk, 16-way k-split
        float* xb = lds;
        float* sp = lds + 4224;
        const int hl = tid & 15, ks = tid >> 4;
        const int h = (bid - 176) * 16 + hl;
        const float* W = Wqr + (ks * 32) * 96 + h;
        float wreg[32];
        #pragma unroll
        for (int k = 0; k < 32; ++k) wreg[k] = W[k * 96];
        for (int k = tid; k < 512; k += 256) xb[k] = x[k];
        __syncthreads();
        const float* xq = xb + ks * 32;
        float acc = 0.f;
        #pragma unroll
        for (int k = 0; k < 32; ++k) acc += xq[k] * wreg[k];
        sp[tid] = acc;
        __syncthreads();
        if (tid < 16) {
            float a = bqr[(bid - 176) * 16 + tid];
            #pragma unroll
            for (int u = 0; u < 16; ++u) a += sp[u * 16 + tid];
            ws[WS_Q + (bid - 176) * 16 + tid] = fmaxf(a, 0.f);
        }
    } else {
        // B-group: pre-stage weights while phase A runs (no ws dependency)
        const int rb = bid - 182;
        if (rb < 48) {
            const int proc = rb & 7, slot = rb >> 3;
            const int mat = slot / 3, t = slot % 3;
            float* sWf1 = lds;            // 9216
            float* sWkv = lds + 9216;     // 3072
            const float4* F4 = (const float4*)fc1w + proc * 2304;
            float4* D4 = (float4*)sWf1;
            #pragma unroll
            for (int r = 0; r < 9; ++r) D4[tid + 256 * r] = F4[tid + 256 * r];
            const float4* KV4 = (const float4*)(mat ? Wv2 : Wk2);
            float4* E4 = (float4*)sWkv;
            #pragma unroll
            for (int r = 0; r < 3; ++r) {
                const int idx = tid + 256 * r;          // 768 float4
                const int row = idx >> 3, q4 = idx & 7;
                E4[row * 8 + q4] = KV4[proc * 2304 + row * 24 + t * 8 + q4];
            }
        } else {
            const int rq = rb - 48, proc = rq & 7, t = rq >> 3;
            const int jl = tid & 31, ks8 = tid >> 5;
            const int j = 32 * t + jl;
            const float* W = Wq2 + proc * 9216 + j;
            #pragma unroll
            for (int i = 0; i < 12; ++i) wq2r[i] = W[(12 * ks8 + i) * 96];
        }
    }

    cg::this_grid().sync();   // ws: QKV, alpha, q now visible device-wide

    // ======================= phase-B window =======================
    float wor[24];            // phase-C Wo prefetch (bids 0..63)
    float der[8] = {0,0,0,0,0,0,0,0};
    float av = 0.f, rg = 0.f;
    if (bid >= 182) {
        const int rb = bid - 182;
        if (rb < 48) {
            const int proc = rb & 7, slot = rb >> 3;
            const int mat = slot / 3, t = slot % 3;
            float* sWf1 = lds;
            float* sWkv = lds + 9216;
            float* sQk = lds + 12288;
            float* sKk = lds + 13056;
            float* sVv = lds + 13824;
            float* sH  = lds + 14592;
            float* sH2 = lds + 15360;
            float* sS  = lds + 16128;    // 192 -> ends at 16320
            const float* qkv = ws + WS_QKV + proc * 2304;
            for (int i = tid; i < 768; i += 256) {
                sQk[i] = qkv[i]; sKk[i] = qkv[768 + i]; sVv[i] = qkv[1536 + i];
            }
            __syncthreads();
            if (tid < 192) {       // attn1 logits (h0, si, sk)
                const int h0 = tid / 64, r64 = tid % 64, si = r64 / 8, sk = r64 % 8;
                float acc = 0.f;
                #pragma unroll
                for (int d = 0; d < 32; ++d)
                    acc += sQk[si * 96 + h0 * 32 + d] * sKk[sk * 96 + h0 * 32 + d];
                sS[tid] = acc * rs;
            }
            __syncthreads();
            if (tid < 24) {        // softmax rows in place
                float* row = sS + tid * 8;
                float mx = row[0];
                #pragma unroll
                for (int k = 1; k < 8; ++k) mx = fmaxf(mx, row[k]);
                float e[8], sum = 0.f;
                #pragma unroll
                for (int k = 0; k < 8; ++k) { e[k] = __expf(row[k] - mx); sum += e[k]; }
                const float inv = 1.f / sum;
                #pragma unroll
                for (int k = 0; k < 8; ++k) row[k] = e[k] * inv;
            }
            __syncthreads();
            if (tid < 192) {       // AV + residual (h0, si, dq): 4 d's each
                const int h0 = tid / 64, r64 = tid % 64, si = r64 / 8, dq = r64 % 8;
                const float* e = sS + h0 * 64 + si * 8;
                float o0 = 0.f, o1 = 0.f, o2 = 0.f, o3 = 0.f;
                #pragma unroll
                for (int k = 0; k < 8; ++k) {
                    const float ek = e[k];
                    const float* v = sVv + k * 96 + h0 * 32 + dq * 4;
                    o0 += ek*v[0]; o1 += ek*v[1]; o2 += ek*v[2]; o3 += ek*v[3];
                }
                const int base = si * 96 + h0 * 32 + dq * 4;
                sH[base+0] = sQk[base+0] + o0;  sH[base+1] = sQk[base+1] + o1;
                sH[base+2] = sQk[base+2] + o2;  sH[base+3] = sQk[base+3] + o3;
            }
            __syncthreads();
            #pragma unroll
            for (int r = 0; r < 3; ++r) {   // fc1, 3 outputs/thread
                const int idx = tid + 256 * r, s = idx / 96, j = idx % 96;
                const float* Hs = sH + s * 96;
                float acc = 0.f;
                #pragma unroll
                for (int i = 0; i < 96; ++i) acc += Hs[i] * sWf1[i * 96 + j];
                sH2[idx] = sH[idx] + fmaxf(acc, 0.f);
            }
            __syncthreads();
            const int s = tid >> 5, jl = tid & 31, j = t * 32 + jl;
            const float* Hs = sH2 + s * 96;
            float acc = 0.f;
            #pragma unroll
            for (int i = 0; i < 96; ++i) acc += Hs[i] * sWkv[i * 32 + jl];
            ws[(mat ? WS_V2 : WS_K2) + proc * 768 + s * 96 + j] = acc;
        } else {
            // Qq = q @ Wq2 (weights already in regs)
            const int rq = rb - 48, proc = rq & 7, t = rq >> 3;
            float* sq  = lds;
            float* spq = lds + 96;
            if (tid < 96) sq[tid] = ws[WS_Q + tid];
            __syncthreads();
            const int jl = tid & 31, ks8 = tid >> 5;
            const int j = 32 * t + jl;
            float acc = 0.f;
            #pragma unroll
            for (int i = 0; i < 12; ++i) acc += sq[12 * ks8 + i] * wq2r[i];
            spq[tid] = acc;
            __syncthreads();
            if (ks8 == 0) {
                float a = 0.f;
                #pragma unroll
                for (int u = 0; u < 8; ++u) a += spq[jl + 32 * u];
                ws[WS_QQ + proc * 96 + j] = a;
            }
        }
    } else if (bid < 64) {
        // C-group: pre-stage fc2 (LDS), Wo (regs), De/alpha/regs/gate while B runs
        const int proc = bid & 7, e = bid >> 3;
        float* sWf2 = lds;                // 9216
        float* sg   = lds + 11168;        // 8
        const float4* F4 = (const float4*)fc2w + proc * 2304;
        float4* D4 = (float4*)sWf2;
        #pragma unroll
        for (int r = 0; r < 9; ++r) D4[tid + 256 * r] = F4[tid + 256 * r];
        const int ml = tid & 63, ksv = tid >> 6;
        const int m = 64 * e + ml;
        const float* Wop = Wo + proc * 49152 + m;
        #pragma unroll
        for (int i = 0; i < 24; ++i) wor[i] = Wop[(24 * ksv + i) * 512];  // coalesced rows
        const float4* Dp4 = (const float4*)(De + proc * 4096 + m * 8);
        const float4 t0 = Dp4[0], t1 = Dp4[1];
        der[0]=t0.x; der[1]=t0.y; der[2]=t0.z; der[3]=t0.w;
        der[4]=t1.x; der[5]=t1.y; der[6]=t1.z; der[7]=t1.w;
        av = ws[WS_ALPHA + m];            // written in phase A, visible post-sync1
        rg = regs[proc * 512 + m];
        if (tid < 8) sg[tid] = gate[tid];
    }

    cg::this_grid().sync();   // ws: K2, V2, Qq now visible device-wide

    // ======================= phase-C window =======================
    if (bid < 64) {
        const int proc = bid & 7, e = bid >> 3;
        float* sWf2 = lds;
        float* sK2 = lds + 9216;
        float* sV2 = lds + 9984;
        float* sQq = lds + 10752;
        float* sO  = lds + 10848;
        float* sOf = lds + 10944;
        float* sE2 = lds + 11040;
        float* sg  = lds + 11168;
        float* spc = lds + 11176;        // 256 -> ends 11432
        const int ml = tid & 63, ksv = tid >> 6;
        const int m = 64 * e + ml;
        for (int i = tid; i < 768; i += 256) {
            sK2[i] = ws[WS_K2 + proc * 768 + i];
            sV2[i] = ws[WS_V2 + proc * 768 + i];
        }
        if (tid < 96) sQq[tid] = ws[WS_QQ + proc * 96 + tid];
        __syncthreads();
        if (tid < 16) {        // attn2 probs: 16 heads, d=6, 1 query row
            const int h0 = tid;
            float lg[8], mx = -1e30f;
            #pragma unroll
            for (int k = 0; k < 8; ++k) {
                float acc = 0.f;
                #pragma unroll
                for (int d = 0; d < 6; ++d)
                    acc += sQq[h0 * 6 + d] * sK2[k * 96 + h0 * 6 + d];
                lg[k] = acc * rs; mx = fmaxf(mx, lg[k]);
            }
            float ex[8], sum = 0.f;
            #pragma unroll
            for (int k = 0; k < 8; ++k) { ex[k] = __expf(lg[k] - mx); sum += ex[k]; }
            const float inv = 1.f / sum;
            #pragma unroll
            for (int k = 0; k < 8; ++k) sE2[h0 * 8 + k] = ex[k] * inv;
        }
        __syncthreads();
        if (tid < 96) {        // AV + residual
            const int h0 = tid / 6;
            float o = 0.f;
            #pragma unroll
            for (int k = 0; k < 8; ++k) o += sE2[h0 * 8 + k] * sV2[k * 96 + tid];
            sO[tid] = sQq[tid] + o;
        }
        __syncthreads();
        if (tid < 192) {       // fc2, 2-way k-split
            const int j = tid % 96, k2 = tid / 96;
            const float* Os = sO + k2 * 48;
            float acc = 0.f;
            #pragma unroll
            for (int i = 0; i < 48; ++i) acc += Os[i] * sWf2[(k2 * 48 + i) * 96 + j];
            spc[tid] = acc;
        }
        __syncthreads();
        if (tid < 96) sOf[tid] = sO[tid] + fmaxf(spc[tid] + spc[96 + tid], 0.f);
        __syncthreads();
        // Wo from prefetched regs: 64 maps, 4-way k-split
        float acc = 0.f;
        #pragma unroll
        for (int i = 0; i < 24; ++i) acc += sOf[24 * ksv + i] * wor[i];
        spc[tid] = acc;
        __syncthreads();
        if (ksv == 0) {
            const float tr = spc[ml] + spc[ml + 64] + spc[ml + 128] + spc[ml + 192];
            const float de = der[0]*sg[0] + der[1]*sg[1] + der[2]*sg[2] + der[3]*sg[3]
                           + der[4]*sg[4] + der[5]*sg[5] + der[6]*sg[6] + der[7]*sg[7];
            const float mix = av * tr + (1.f - av) * de;
            const int pt = proc & 3;                 // gamma gets +1, beta not
            const float off = (pt == 0 || pt == 2) ? 1.f : 0.f;
            out[proc * 512 + m] = mix * rg + off;
        }
    }
}

extern "C" void kernel_launch(void* const* d_in, const int* in_sizes, int n_in,
                              void* d_out, int out_size, void* d_ws, size_t ws_size,
                              hipStream_t stream)
{
    const float* gate = (const float*)d_in[0];
    const float* x    = (const float*)d_in[1];
    const float* Wa   = (const float*)d_in[2];
    const float* ba   = (const float*)d_in[3];
    const float* Wqr  = (const float*)d_in[4];
    const float* bqr  = (const float*)d_in[5];
    const float* P    = (const float*)d_in[6];
    const float* De   = (const float*)d_in[7];
    const float* regs = (const float*)d_in[8];
    const float* Wq1  = (const float*)d_in[9];
    const float* Wk1  = (const float*)d_in[10];
    const float* Wv1  = (const float*)d_in[11];
    const float* fc1  = (const float*)d_in[12];
    const float* Wq2  = (const float*)d_in[13];
    const float* Wk2  = (const float*)d_in[14];
    const float* Wv2  = (const float*)d_in[15];
    const float* fc2  = (const float*)d_in[16];
    const float* Wo   = (const float*)d_in[17];
    float* ws   = (float*)d_ws;
    float* outp = (float*)d_out;

    void* args[] = {
        (void*)&gate, (void*)&x, (void*)&Wa, (void*)&ba, (void*)&Wqr, (void*)&bqr,
        (void*)&P, (void*)&De, (void*)&regs, (void*)&Wq1, (void*)&Wk1, (void*)&Wv1,
        (void*)&fc1, (void*)&Wq2, (void*)&Wk2, (void*)&Wv2, (void*)&fc2, (void*)&Wo,
        (void*)&ws, (void*)&outp
    };
    hipLaunchCooperativeKernel((void*)fused_film, dim3(254), dim3(256),
                               args, 0, stream);
}

// Round 2
// 106.702 us; speedup vs baseline: 1.7802x; 1.7802x over previous
//
#include <hip/hip_runtime.h>
#include <hip/hip_bf16.h>
#include <math.h>

// NUM_MAPS=512, ZG=512, HID=96, SEQ=8, H1=3, H2=16, NPROC=8. fp32 in/out.
// R14 post-mortem: cooperative single-kernel FAILED (190us). grid.sync() on
// 254 blocks costs ~25us each on 8 XCDs (fused kernel = 66us, VALUBusy 1.4%)
// and cooperative launch adds ~30us of non-graphable overhead. Kernel-count
// bracket confirmed: {1:138(tax), 2:110.5, 3:107.9*, 6:115.9, 7:116.6}.
// R15: revert to R13 3-kernel structure + L2 warming. kA uses only 182 of
// 256 CUs; 74 extra warm blocks (bid 182..255) stream kB/kC's weights
// (fc1/fc2/Wq2/Wk2/Wv2/Wo/De, ~380KB/proc) into the consumer XCD's L2
// (bid%8 == proc, matching kB/kC's proc = blk&7 placement) while kA runs.
// The per-iteration 256MB ws re-poison flushes caches, so kB/kC entry
// bursts otherwise pay cold-HBM latency serially at kernel entry.

#define WS_ALPHA 0
#define WS_Q     512
#define WS_QKV   608      // 8*2304 -> 19040
#define WS_K2    19040    // 8*768  -> 25184
#define WS_V2    25184    // 8*768  -> 31328
#define WS_QQ    31328    // 8*96   -> 32096
#define WS_SINK  32768    // warm-block DCE sink (scratch)

// ---------------------------------------------------------------------------
// KA (256 x 256):
//  blk 0..143   : QKV1. proc = blk%8 (XCD), rem = blk/8 -> (mat, six).
//  blk 144..175 : alpha. 16 m/blk, 16-way k-split, W hoisted.
//  blk 176..181 : q. 16 h/blk, 16-way k-split, W hoisted.
//  blk 182..255 : L2 warm of phase-B/C weights on XCD (blk%8).
// ---------------------------------------------------------------------------
__global__ __launch_bounds__(256) void kA_qkv_alpha_q(
    const float* __restrict__ x, const float* __restrict__ Wa,
    const float* __restrict__ ba, const float* __restrict__ Wqr,
    const float* __restrict__ bqr, const float* __restrict__ P,
    const float* __restrict__ Wq1, const float* __restrict__ Wk1,
    const float* __restrict__ Wv1,
    const float* __restrict__ fc1w, const float* __restrict__ Wq2,
    const float* __restrict__ Wk2, const float* __restrict__ Wv2,
    const float* __restrict__ fc2w, const float* __restrict__ Wo,
    const float* __restrict__ De, float* __restrict__ ws)
{
    __shared__ float sK[8 * 528];   // skewed K tile (c -> c + c/32), or x
    __shared__ float sp[2048];      // partial sums
    const int blk = blockIdx.x, tid = threadIdx.x;

    if (blk < 144) {
        const int proc = blk & 7, rem = blk >> 3;       // proc -> XCD
        const int mat = rem / 6, six = rem % 6;
        const int hl = tid & 15, ks = tid >> 4;        // ks 0..15
        const int h = six * 16 + hl;
        const float* W = (mat == 0 ? Wq1 : (mat == 1 ? Wk1 : Wv1))
                         + proc * 49152 + (ks * 32) * 96 + h;
        float wreg[32];
        #pragma unroll
        for (int m2 = 0; m2 < 32; ++m2) wreg[m2] = W[m2 * 96];  // issued early
        const float4* P4 = (const float4*)(P + proc * 4096);
        for (int i = tid; i < 1024; i += 256) {
            float4 v = P4[i];
            const int c = i >> 1, off = (i & 1) * 4;
            const int cp = c + (c >> 5);
            sK[(off + 0) * 528 + cp] = v.x;
            sK[(off + 1) * 528 + cp] = v.y;
            sK[(off + 2) * 528 + cp] = v.z;
            sK[(off + 3) * 528 + cp] = v.w;
        }
        __syncthreads();
        const float* Kb = sK + ks * 33;                // skewed base
        float acc[8] = {0.f,0.f,0.f,0.f,0.f,0.f,0.f,0.f};
        #pragma unroll
        for (int m2 = 0; m2 < 32; ++m2) {
            const float w = wreg[m2];
            const float* Kc = Kb + m2;
            #pragma unroll
            for (int s = 0; s < 8; ++s) acc[s] += Kc[s * 528] * w;
        }
        float* spb = sp + ks * 128 + hl * 8;
        #pragma unroll
        for (int s = 0; s < 8; ++s) spb[s] = acc[s];
        __syncthreads();
        if (tid < 128) {            // tid = hl2*8 + s
            float a = 0.f;
            #pragma unroll
            for (int u = 0; u < 16; ++u) a += sp[u * 128 + tid];
            const int hl2 = tid >> 3, s = tid & 7;
            ws[WS_QKV + proc * 2304 + mat * 768 + s * 96 + six * 16 + hl2] = a;
        }
    } else if (blk < 176) {
        const int ml = tid & 15, ks = tid >> 4;        // 32 k each
        const int m = (blk - 144) * 16 + ml;
        const float* W = Wa + (ks * 32) * 512 + m;
        float wreg[32];
        #pragma unroll
        for (int k = 0; k < 32; ++k) wreg[k] = W[k * 512];
        for (int k = tid; k < 512; k += 256) sK[k] = x[k];
        __syncthreads();
        const float* xq = sK + ks * 32;
        float acc = 0.f;
        #pragma unroll
        for (int k = 0; k < 32; ++k) acc += xq[k] * wreg[k];
        sp[tid] = acc;
        __syncthreads();
        if (tid < 16) {
            float a = ba[(blk - 144) * 16 + tid];
            #pragma unroll
            for (int u = 0; u < 16; ++u) a += sp[u * 16 + tid];
            ws[WS_ALPHA + (blk - 144) * 16 + tid] = 1.f / (1.f + __expf(-a));
        }
    } else if (blk < 182) {
        const int hl = tid & 15, ks = tid >> 4;        // 32 k each
        const int h = (blk - 176) * 16 + hl;           // 6*16 = 96
        const float* W = Wqr + (ks * 32) * 96 + h;
        float wreg[32];
        #pragma unroll
        for (int k = 0; k < 32; ++k) wreg[k] = W[k * 96];
        for (int k = tid; k < 512; k += 256) sK[k] = x[k];
        __syncthreads();
        const float* xq = sK + ks * 32;
        float acc = 0.f;
        #pragma unroll
        for (int k = 0; k < 32; ++k) acc += xq[k] * wreg[k];
        sp[tid] = acc;
        __syncthreads();
        if (tid < 16) {
            float a = bqr[(blk - 176) * 16 + tid];
            #pragma unroll
            for (int u = 0; u < 16; ++u) a += sp[u * 16 + tid];
            ws[WS_Q + (blk - 176) * 16 + tid] = fmaxf(a, 0.f);
        }
    } else {
        // L2 warm: stream phase-B/C weights for proc = blk%8 into this XCD's
        // L2 while the real kA blocks compute. ~9-10 chunks per proc.
        const int wb = blk - 182;                      // 0..73
        const int proc = blk & 7;                      // consumer XCD match
        const int chunk = wb >> 3;                     // 0..9
        float acc = 0.f;
        const int base = chunk * 256 + tid;
        const int stride = 10 * 256;
        #define WARM(ptr, n4)                                            \
        {                                                                \
            const float4* p4 = (const float4*)(ptr);                     \
            for (int i = base; i < (n4); i += stride) {                  \
                float4 v = p4[i];                                        \
                acc += v.x + v.y + v.z + v.w;                            \
            }                                                            \
        }
        WARM(fc1w + proc * 9216, 2304);
        WARM(fc2w + proc * 9216, 2304);
        WARM(Wq2  + proc * 9216, 2304);
        WARM(Wk2  + proc * 9216, 2304);
        WARM(Wv2  + proc * 9216, 2304);
        WARM(Wo   + proc * 49152, 12288);
        WARM(De   + proc * 4096, 1024);
        #undef WARM
        if (tid == 0) ws[WS_SINK + blk] = acc;         // keep loads live
    }
}

// ---------------------------------------------------------------------------
// KB (72 x 256): blk<48: proc = blk%8 (XCD), slot = blk/8 -> (mat, t).
// Entry burst-stages fc1 (36KB, 6x L2-shared) + Wk2/Wv2 slice (12KB) into
// LDS, then attn1 -> fc1 -> K2/V2 slice.
// blk 48..71: Qq = q @ Wq2; proc = (blk-48)%8, t = (blk-48)/8.
// ---------------------------------------------------------------------------
__global__ __launch_bounds__(256) void kB_attn1_fc1_kv2(
    const float* __restrict__ fc1w, const float* __restrict__ Wk2,
    const float* __restrict__ Wv2, const float* __restrict__ Wq2,
    float* __restrict__ ws)
{
    const int b = blockIdx.x, tid = threadIdx.x;
    const float rs = 0.10206207261596577f;  // 1/sqrt(96)

    if (b < 48) {
        const int proc = b & 7, slot = b >> 3;          // proc -> XCD
        const int mat = slot / 3, t = slot % 3;
        __shared__ float sQk[768], sKk[768], sVv[768], sH[768], sH2[768], sS[192];
        __shared__ float sWf1[9216];     // fc1, row-major [i][j]
        __shared__ float sWkv[96 * 32];  // Wk2/Wv2 column slice [i][jl]

        // ---- entry burst: all weight bytes, coalesced float4, once ----
        {
            const float4* F4 = (const float4*)fc1w + proc * 2304;
            float4* D4 = (float4*)sWf1;
            #pragma unroll
            for (int r = 0; r < 9; ++r) D4[tid + 256 * r] = F4[tid + 256 * r];
            const float4* KV4 = (const float4*)(mat ? Wv2 : Wk2);
            float4* E4 = (float4*)sWkv;
            #pragma unroll
            for (int r = 0; r < 3; ++r) {
                const int idx = tid + 256 * r;          // 768 float4
                const int row = idx >> 3, q4 = idx & 7;
                E4[row * 8 + q4] = KV4[proc * 2304 + row * 24 + t * 8 + q4];
            }
        }
        const float* qkv = ws + WS_QKV + proc * 2304;
        for (int i = tid; i < 768; i += 256) {
            sQk[i] = qkv[i]; sKk[i] = qkv[768 + i]; sVv[i] = qkv[1536 + i];
        }
        __syncthreads();

        if (tid < 192) {       // attn1 logits (h0, si, sk)
            const int h0 = tid / 64, r64 = tid % 64, si = r64 / 8, sk = r64 % 8;
            float acc = 0.f;
            #pragma unroll
            for (int d = 0; d < 32; ++d)
                acc += sQk[si * 96 + h0 * 32 + d] * sKk[sk * 96 + h0 * 32 + d];
            sS[tid] = acc * rs;
        }
        __syncthreads();
        if (tid < 24) {        // softmax row -> probs in place
            float* row = sS + tid * 8;
            float mx = row[0];
            #pragma unroll
            for (int k = 1; k < 8; ++k) mx = fmaxf(mx, row[k]);
            float e[8], sum = 0.f;
            #pragma unroll
            for (int k = 0; k < 8; ++k) { e[k] = __expf(row[k] - mx); sum += e[k]; }
            const float inv = 1.f / sum;
            #pragma unroll
            for (int k = 0; k < 8; ++k) row[k] = e[k] * inv;
        }
        __syncthreads();
        if (tid < 192) {       // AV + residual (h0, si, dq): 4 d's each
            const int h0 = tid / 64, r64 = tid % 64, si = r64 / 8, dq = r64 % 8;
            const float* e = sS + h0 * 64 + si * 8;
            float o0 = 0.f, o1 = 0.f, o2 = 0.f, o3 = 0.f;
            #pragma unroll
            for (int k = 0; k < 8; ++k) {
                const float ek = e[k];
                const float* v = sVv + k * 96 + h0 * 32 + dq * 4;
                o0 += ek*v[0]; o1 += ek*v[1]; o2 += ek*v[2]; o3 += ek*v[3];
            }
            const int base = si * 96 + h0 * 32 + dq * 4;
            sH[base+0] = sQk[base+0] + o0;  sH[base+1] = sQk[base+1] + o1;
            sH[base+2] = sQk[base+2] + o2;  sH[base+3] = sQk[base+3] + o3;
        }
        __syncthreads();
        // fc1 from LDS (full, redundant): 3 outputs/thread
        #pragma unroll
        for (int r = 0; r < 3; ++r) {
            const int idx = tid + 256 * r, s = idx / 96, j = idx % 96;
            const float* Hs = sH + s * 96;
            float acc = 0.f;
            #pragma unroll
            for (int i = 0; i < 96; ++i) acc += Hs[i] * sWf1[i * 96 + j];
            sH2[idx] = sH[idx] + fmaxf(acc, 0.f);
        }
        __syncthreads();
        // K2/V2 slice from LDS: (s, jl)
        const int s = tid >> 5, jl = tid & 31, j = t * 32 + jl;
        const float* Hs = sH2 + s * 96;
        float acc = 0.f;
        #pragma unroll
        for (int i = 0; i < 96; ++i) acc += Hs[i] * sWkv[i * 32 + jl];
        ws[(mat ? WS_V2 : WS_K2) + proc * 768 + s * 96 + j] = acc;
    } else {
        const int b2 = b - 48, proc = b2 & 7, t = b2 >> 3;   // proc -> XCD
        __shared__ float sq[96], sp[256];
        if (tid < 96) sq[tid] = ws[WS_Q + tid];
        __syncthreads();
        const int jl = tid & 31, ks = tid >> 5;
        const int j = 32 * t + jl;
        const float* W = Wq2 + proc * 9216 + j;
        float acc = 0.f;
        #pragma unroll
        for (int i = 0; i < 12; ++i)
            acc += sq[12 * ks + i] * W[(12 * ks + i) * 96];
        sp[tid] = acc;
        __syncthreads();
        if (ks == 0) {
            float a = 0.f;
            #pragma unroll
            for (int u = 0; u < 8; ++u) a += sp[jl + 32 * u];
            ws[WS_QQ + proc * 96 + j] = a;
        }
    }
}

// ---------------------------------------------------------------------------
// KC (64 x 256): proc = blk%8 (XCD), e = blk/8. Entry burst-stages fc2
// (36KB, 8x L2-shared) + Wo slice (24KB) into LDS + K2/V2/Qq from ws +
// De/alpha/regs into regs. Then attn2, fc2, Wo slice + epilogue.
// ---------------------------------------------------------------------------
__global__ __launch_bounds__(256) void kC_attn2_fc2_out(
    const float* __restrict__ gate, const float* __restrict__ De,
    const float* __restrict__ regs, const float* __restrict__ fc2w,
    const float* __restrict__ Wo, const float* __restrict__ ws,
    float* __restrict__ out)
{
    const int b = blockIdx.x, proc = b & 7, e = b >> 3, tid = threadIdx.x;
    __shared__ float sK2[768], sV2[768];
    __shared__ float sQq[96], sO[96], sOf[96], sE2[128], sg[8], sp[256];
    __shared__ float sWf2[9216];     // fc2 [i][j]
    __shared__ float sWo[96 * 64];   // Wo slice [h][ml]
    const float rs = 0.10206207261596577f;

    // ---- entry burst ----
    {
        const float4* F4 = (const float4*)fc2w + proc * 2304;
        float4* D4 = (float4*)sWf2;
        #pragma unroll
        for (int r = 0; r < 9; ++r) D4[tid + 256 * r] = F4[tid + 256 * r];
        const float4* W4 = (const float4*)Wo;
        float4* E4 = (float4*)sWo;
        #pragma unroll
        for (int r = 0; r < 6; ++r) {
            const int idx = tid + 256 * r;              // 1536 float4
            const int row = idx >> 4, q4 = idx & 15;
            E4[row * 16 + q4] = W4[proc * 12288 + row * 128 + e * 16 + q4];
        }
    }
    const int ml = tid & 63, ks = tid >> 6;
    const int m = 64 * e + ml;
    // epilogue operands prefetched into regs (redundant across ks, cheap)
    const float4* Dp4 = (const float4*)(De + proc * 4096 + m * 8);
    const float4 d0 = Dp4[0], d1 = Dp4[1];
    const float av = ws[WS_ALPHA + m];
    const float rg = regs[proc * 512 + m];
    for (int i = tid; i < 768; i += 256) {
        sK2[i] = ws[WS_K2 + proc * 768 + i];
        sV2[i] = ws[WS_V2 + proc * 768 + i];
    }
    if (tid < 96) sQq[tid] = ws[WS_QQ + proc * 96 + tid];
    else if (tid >= 96 && tid < 104) sg[tid - 96] = gate[tid - 96];
    __syncthreads();

    // attn2 probs: 16 heads, d=6, 1 query row
    if (tid < 16) {
        const int h0 = tid;
        float lg[8], mx = -1e30f;
        #pragma unroll
        for (int k = 0; k < 8; ++k) {
            float acc = 0.f;
            #pragma unroll
            for (int d = 0; d < 6; ++d)
                acc += sQq[h0 * 6 + d] * sK2[k * 96 + h0 * 6 + d];
            lg[k] = acc * rs; mx = fmaxf(mx, lg[k]);
        }
        float ex[8], sum = 0.f;
        #pragma unroll
        for (int k = 0; k < 8; ++k) { ex[k] = __expf(lg[k] - mx); sum += ex[k]; }
        const float inv = 1.f / sum;
        #pragma unroll
        for (int k = 0; k < 8; ++k) sE2[h0 * 8 + k] = ex[k] * inv;
    }
    __syncthreads();
    if (tid < 96) {           // AV + residual
        const int h0 = tid / 6;
        float o = 0.f;
        #pragma unroll
        for (int k = 0; k < 8; ++k) o += sE2[h0 * 8 + k] * sV2[k * 96 + tid];
        sO[tid] = sQq[tid] + o;
    }
    __syncthreads();
    if (tid < 192) {          // fc2 from LDS, 2-way k-split
        const int j = tid % 96, k2 = tid / 96;
        const float* Os = sO + k2 * 48;
        float acc = 0.f;
        #pragma unroll
        for (int i = 0; i < 48; ++i) acc += Os[i] * sWf2[(k2 * 48 + i) * 96 + j];
        sp[tid] = acc;
    }
    __syncthreads();
    if (tid < 96) sOf[tid] = sO[tid] + fmaxf(sp[tid] + sp[96 + tid], 0.f);
    __syncthreads();

    // Wo slice from LDS: 64 maps, 4-way k-split
    float acc = 0.f;
    #pragma unroll
    for (int i = 0; i < 24; ++i)
        acc += sOf[24 * ks + i] * sWo[(24 * ks + i) * 64 + ml];
    sp[tid] = acc;
    __syncthreads();
    if (ks == 0) {
        const float tr = sp[ml] + sp[ml + 64] + sp[ml + 128] + sp[ml + 192];
        const float de = d0.x * sg[0] + d0.y * sg[1] + d0.z * sg[2] + d0.w * sg[3]
                       + d1.x * sg[4] + d1.y * sg[5] + d1.z * sg[6] + d1.w * sg[7];
        const float mix = av * tr + (1.f - av) * de;
        const int pt = proc & 3;                 // gamma gets +1, beta not
        const float off = (pt == 0 || pt == 2) ? 1.f : 0.f;
        out[proc * 512 + m] = mix * rg + off;
    }
}

extern "C" void kernel_launch(void* const* d_in, const int* in_sizes, int n_in,
                              void* d_out, int out_size, void* d_ws, size_t ws_size,
                              hipStream_t stream)
{
    const float* gate = (const float*)d_in[0];
    const float* x    = (const float*)d_in[1];
    const float* Wa   = (const float*)d_in[2];
    const float* ba   = (const float*)d_in[3];
    const float* Wqr  = (const float*)d_in[4];
    const float* bqr  = (const float*)d_in[5];
    const float* P    = (const float*)d_in[6];
    const float* De   = (const float*)d_in[7];
    const float* regs = (const float*)d_in[8];
    const float* Wq1  = (const float*)d_in[9];
    const float* Wk1  = (const float*)d_in[10];
    const float* Wv1  = (const float*)d_in[11];
    const float* fc1  = (const float*)d_in[12];
    const float* Wq2  = (const float*)d_in[13];
    const float* Wk2  = (const float*)d_in[14];
    const float* Wv2  = (const float*)d_in[15];
    const float* fc2  = (const float*)d_in[16];
    const float* Wo   = (const float*)d_in[17];
    float* ws = (float*)d_ws;

    hipLaunchKernelGGL(kA_qkv_alpha_q, dim3(256), dim3(256), 0, stream,
                       x, Wa, ba, Wqr, bqr, P, Wq1, Wk1, Wv1,
                       fc1, Wq2, Wk2, Wv2, fc2, Wo, De, ws);
    hipLaunchKernelGGL(kB_attn1_fc1_kv2, dim3(72), dim3(256), 0, stream,
                       fc1, Wk2, Wv2, Wq2, ws);
    hipLaunchKernelGGL(kC_attn2_fc2_out, dim3(64), dim3(256), 0, stream,
                       gate, De, regs, fc2, Wo, ws, (float*)d_out);
}